// Round 1
// baseline (40.384 us; speedup 1.0000x reference)
//
#include <hip/hip_runtime.h>

#define BB 8
#define NN 2048
#define TT 512
#define DD 32
#define SS (NN + TT)   // 2560 total nodes per batch

// ws layout (floats): rowL[B*SS] | rowR[B*SS] | colS[B*SS] | colT[B*SS]
//  rowL[b,r]: row score used for columns c <  N
//  rowR[b,r]: row score used for columns c >= N
//  colS[b,c]: col score (+bias) used for rows r <  N  (spatial rows)
//  colT[b,c]: col score (+bias) used for rows r >= N  (temporal rows)

__global__ __launch_bounds__(256) void precompute_scores(
    const float* __restrict__ sp,   // (B, N, D)
    const float* __restrict__ tp,   // (B, T, D)
    const float* __restrict__ w_ss, const float* __restrict__ b_ss,
    const float* __restrict__ w_tt, const float* __restrict__ b_tt,
    const float* __restrict__ w_st, const float* __restrict__ b_st,
    const float* __restrict__ w_ts, const float* __restrict__ b_ts,
    float* __restrict__ ws)
{
    int idx = blockIdx.x * blockDim.x + threadIdx.x;  // b*SS + i
    if (idx >= BB * SS) return;
    int b = idx / SS;
    int i = idx - b * SS;

    const float *v, *wl, *wr, *wcs, *wct;
    float bs, bt;
    if (i < NN) {
        // spatial node: rows use w_ss/w_st (lo half); cols use w_ss/w_ts (hi half)
        v   = sp + ((size_t)b * NN + i) * DD;
        wl  = w_ss;       wr  = w_st;
        wcs = w_ss + DD;  wct = w_ts + DD;
        bs  = b_ss[0];    bt  = b_ts[0];
    } else {
        // temporal node: rows use w_ts/w_tt (lo half); cols use w_st/w_tt (hi half)
        v   = tp + ((size_t)b * TT + (i - NN)) * DD;
        wl  = w_ts;       wr  = w_tt;
        wcs = w_st + DD;  wct = w_tt + DD;
        bs  = b_st[0];    bt  = b_tt[0];
    }

    float aL = 0.f, aR = 0.f, aS = 0.f, aT = 0.f;
#pragma unroll
    for (int d = 0; d < DD; ++d) {
        float x = v[d];
        aL = fmaf(x, wl[d],  aL);
        aR = fmaf(x, wr[d],  aR);
        aS = fmaf(x, wcs[d], aS);
        aT = fmaf(x, wct[d], aT);
    }

    float* rowL = ws;
    float* rowR = ws + 1 * BB * SS;
    float* colS = ws + 2 * BB * SS;
    float* colT = ws + 3 * BB * SS;
    rowL[idx] = aL;
    rowR[idx] = aR;
    colS[idx] = aS + bs;
    colT[idx] = aT + bt;
}

__device__ __forceinline__ float tanh_relu(float x) {
    float t = fmaxf(x, 0.f);
    // tanh(t) = 1 - 2/(exp(2t)+1); exact 0 at t=0 (rcp(2.0)=0.5 exactly)
    float e = __expf(2.f * t);
    return fmaf(-2.f, __builtin_amdgcn_rcpf(e + 1.f), 1.f);
}

// One block per output row (b, r); 640 threads x float4 = 2560 floats.
__global__ __launch_bounds__(640) void adj_kernel(
    const float* __restrict__ ws, float* __restrict__ out)
{
    int bid = blockIdx.x;          // b*SS + r
    int b = bid / SS;
    int r = bid - b * SS;

    const float* rowL = ws;
    const float* rowR = ws + 1 * BB * SS;
    const float* colS = ws + 2 * BB * SS;
    const float* colT = ws + 3 * BB * SS;

    float rL = rowL[bid];
    float rR = rowR[bid];
    const float* col = ((r < NN) ? colS : colT) + (size_t)b * SS;

    int c4 = threadIdx.x;                 // 0..639, each handles 4 columns
    float4 cv = ((const float4*)col)[c4];
    float rv = (c4 < NN / 4) ? rL : rR;   // N divisible by 4: no straddle

    float4 o;
    o.x = tanh_relu(rv + cv.x);
    o.y = tanh_relu(rv + cv.y);
    o.z = tanh_relu(rv + cv.z);
    o.w = tanh_relu(rv + cv.w);

    ((float4*)(out + (size_t)bid * SS))[c4] = o;
}

extern "C" void kernel_launch(void* const* d_in, const int* in_sizes, int n_in,
                              void* d_out, int out_size, void* d_ws, size_t ws_size,
                              hipStream_t stream) {
    const float* sp   = (const float*)d_in[0];
    const float* tp   = (const float*)d_in[1];
    const float* w_ss = (const float*)d_in[2];
    const float* b_ss = (const float*)d_in[3];
    const float* w_tt = (const float*)d_in[4];
    const float* b_tt = (const float*)d_in[5];
    const float* w_st = (const float*)d_in[6];
    const float* b_st = (const float*)d_in[7];
    const float* w_ts = (const float*)d_in[8];
    const float* b_ts = (const float*)d_in[9];
    float* out = (float*)d_out;
    float* ws  = (float*)d_ws;   // needs 4*B*SS*4 = 320 KB

    int nscore = BB * SS;  // 20480
    precompute_scores<<<(nscore + 255) / 256, 256, 0, stream>>>(
        sp, tp, w_ss, b_ss, w_tt, b_tt, w_st, b_st, w_ts, b_ts, ws);

    adj_kernel<<<BB * SS, 640, 0, stream>>>(ws, out);
}